// Round 1
// baseline (82.062 us; speedup 1.0000x reference)
//
#include <hip/hip_runtime.h>
#include <hip/hip_bf16.h>

// Problem constants (setup_inputs): x[1024][512] f32, weight[512][16384] f32, L=32
#define B_DIM 1024
#define D_DIM 512
#define N_DIM 16384

typedef __attribute__((ext_vector_type(8))) short bf16x8;
typedef __attribute__((ext_vector_type(4))) float f32x4;

// ws layout (bytes):
//   0   : u32 maxx_bits, u32 maxw_bits
//   8   : f32 sx, st, s(=sx*st), q1
//   1024    : bias   f32[N]        (64 KiB)
//   66560   : badd   f32[N]        (64 KiB)   badd[n] = 32*q1*rint(bias[n]/st)
//   132096  : xq     bf16[B][D]    (1 MiB)
//   1180672 : wqT    bf16[N][D]    (16 MiB)
#define OFF_BIAS 1024
#define OFF_BADD 66560
#define OFF_XQ   132096
#define OFF_WQT  1180672

__device__ inline void gload16(const void* g, void* l) {
  __builtin_amdgcn_global_load_lds((const __attribute__((address_space(1))) void*)g,
                                   (__attribute__((address_space(3))) void*)l, 16, 0, 0);
}

__device__ inline unsigned short f2bf(float f) {
  // values here are integers |v| <= 127 -> low 16 bits of f32 are zero -> exact
  return (unsigned short)(__float_as_uint(f) >> 16);
}

__global__ void k_init(unsigned* u) {
  if (threadIdx.x == 0) { u[0] = 0u; u[1] = 0u; }
}

__global__ __launch_bounds__(256) void k_maxx(const float* __restrict__ x, unsigned* u) {
  __shared__ float red[256];
  const int t = threadIdx.x;
  float m = 0.f;
  const float4* x4 = (const float4*)x;
  const int n4 = B_DIM * D_DIM / 4;
  for (int i = blockIdx.x * 256 + t; i < n4; i += gridDim.x * 256) {
    float4 v = x4[i];
    m = fmaxf(m, fmaxf(fmaxf(fabsf(v.x), fabsf(v.y)), fmaxf(fabsf(v.z), fabsf(v.w))));
  }
  red[t] = m; __syncthreads();
  for (int s = 128; s > 0; s >>= 1) { if (t < s) red[t] = fmaxf(red[t], red[t + s]); __syncthreads(); }
  if (t == 0) atomicMax(u, __float_as_uint(red[0]));
}

// per-column sum of squares (-> bias) + global max|w|
__global__ __launch_bounds__(256) void k_wstats(const float* __restrict__ w,
                                                float* __restrict__ bias,
                                                unsigned* __restrict__ u) {
  __shared__ float sred[256], mred[256];
  const int t = threadIdx.x;
  const int c = t & 63, part = t >> 6;
  const int col = blockIdx.x * 64 + c;
  float ss = 0.f, mx = 0.f;
  const float* p = w + (size_t)part * 128 * N_DIM + col;
  #pragma unroll 4
  for (int d = 0; d < 128; ++d) {
    float v = p[(size_t)d * N_DIM];
    ss += v * v;
    mx = fmaxf(mx, fabsf(v));
  }
  sred[t] = ss; mred[t] = mx;
  __syncthreads();
  if (t < 64) bias[col] = (sred[t] + sred[t + 64] + sred[t + 128] + sred[t + 192]) * (1.0f / 32.0f);
  for (int s = 128; s > 0; s >>= 1) { if (t < s) mred[t] = fmaxf(mred[t], mred[t + s]); __syncthreads(); }
  if (t == 0) atomicMax(u + 1, __float_as_uint(mred[0]));
}

// reduce max(bias) ; compute scales
__global__ __launch_bounds__(256) void k_scales(const float* __restrict__ bias,
                                                float* __restrict__ sc,
                                                const unsigned* __restrict__ u) {
  __shared__ float red[256];
  const int t = threadIdx.x;
  float m = 0.f;
  for (int i = t; i < N_DIM; i += 256) m = fmaxf(m, bias[i]);
  red[t] = m; __syncthreads();
  for (int s = 128; s > 0; s >>= 1) { if (t < s) red[t] = fmaxf(red[t], red[t + s]); __syncthreads(); }
  if (t == 0) {
    float maxt = fmaxf(__uint_as_float(u[1]), red[0]);         // max(|w|, bias) — bias >= 0
    float st = fmaxf(maxt / 127.0f, 1e-12f);
    float maxx = fmaxf(__uint_as_float(u[0]), 1.0f);           // x padded with ones
    float sx = fmaxf(maxx / 127.0f, 1e-12f);
    sc[0] = sx; sc[1] = st; sc[2] = sx * st; sc[3] = rintf(1.0f / sx);
  }
}

__global__ __launch_bounds__(256) void k_badd(const float* __restrict__ bias,
                                              float* __restrict__ badd,
                                              const float* __restrict__ sc) {
  const int i = blockIdx.x * 256 + threadIdx.x;
  badd[i] = 32.0f * sc[3] * rintf(bias[i] / sc[1]);
}

__global__ __launch_bounds__(256) void k_qx(const float* __restrict__ x,
                                            unsigned short* __restrict__ xq,
                                            const float* __restrict__ sc) {
  const int i = blockIdx.x * 256 + threadIdx.x;   // one float4 per thread
  const float sx = sc[0];
  float4 v = ((const float4*)x)[i];
  ushort4 o;
  o.x = f2bf(rintf(v.x / sx));
  o.y = f2bf(rintf(v.y / sx));
  o.z = f2bf(rintf(v.z / sx));
  o.w = f2bf(rintf(v.w / sx));
  ((ushort4*)xq)[i] = o;
}

// quantize + transpose weight: wqT[n][k] = quant(w[k][n]), bf16
__global__ __launch_bounds__(256) void k_qwT(const float* __restrict__ w,
                                             unsigned short* __restrict__ wqT,
                                             const float* __restrict__ sc) {
  __shared__ float tile[64][65];
  const int t = threadIdx.x;
  const int tx = t & 63, ty = t >> 6;
  const int n0 = blockIdx.x * 64, k0 = blockIdx.y * 64;
  const float st = sc[1];
  #pragma unroll
  for (int i = 0; i < 16; ++i) {
    int r = i * 4 + ty;
    tile[r][tx] = w[(size_t)(k0 + r) * N_DIM + n0 + tx];
  }
  __syncthreads();
  #pragma unroll
  for (int i = 0; i < 16; ++i) {
    int nl = i * 4 + ty;
    wqT[(size_t)(n0 + nl) * D_DIM + k0 + tx] = f2bf(rintf(tile[tx][nl] / st));
  }
}

// GEMM: out[b][n] = (sum_k xq[b][k]*wqT[n][k] + badd[n]) * s
// m97 structure: 128x128 tile, BK=32, 4 waves (2x2), 16x16x32 bf16 MFMA,
// global_load_lds width-16 staging, 2 barriers per K-step.
#define BM 128
#define BN 128
#define BK 32

__global__ __launch_bounds__(256) void k_gemm(const unsigned short* __restrict__ xq,
                                              const unsigned short* __restrict__ wqT,
                                              const float* __restrict__ badd,
                                              const float* __restrict__ sc,
                                              float* __restrict__ out) {
  __shared__ __align__(16) short lds_a[BM * BK];  // [128][32] bf16
  __shared__ __align__(16) short lds_b[BN * BK];  // [128 n][32 k]
  const int t = threadIdx.x;
  const int lane = t & 63, w = t >> 6;
  const int wr = w >> 1, wc = w & 1;
  const int n0 = blockIdx.x * BN, m0 = blockIdx.y * BM;

  f32x4 acc[4][4] = {};
  const float s = sc[2];

  for (int kt = 0; kt < D_DIM / BK; ++kt) {
    const int k0 = kt * BK;
    // stage A and B tiles: per issue, 256 threads x 16B = 4096B (64 rows)
    #pragma unroll
    for (int i = 0; i < 2; ++i) {
      const int row = i * 64 + (t >> 2);
      const int ko = (t & 3) * 8;
      gload16(xq + (size_t)(m0 + row) * D_DIM + k0 + ko, &lds_a[i * 2048 + w * 512]);
      gload16(wqT + (size_t)(n0 + row) * D_DIM + k0 + ko, &lds_b[i * 2048 + w * 512]);
    }
    __syncthreads();   // drains vmcnt: LDS tiles complete

    bf16x8 af[4], bfr[4];
    #pragma unroll
    for (int m = 0; m < 4; ++m) {
      const int row = wr * 64 + m * 16 + (lane & 15);
      af[m] = *(const bf16x8*)&lds_a[row * BK + (lane >> 4) * 8];
    }
    #pragma unroll
    for (int n = 0; n < 4; ++n) {
      const int row = wc * 64 + n * 16 + (lane & 15);
      bfr[n] = *(const bf16x8*)&lds_b[row * BK + (lane >> 4) * 8];
    }
    #pragma unroll
    for (int m = 0; m < 4; ++m)
      #pragma unroll
      for (int n = 0; n < 4; ++n)
        acc[m][n] = __builtin_amdgcn_mfma_f32_16x16x32_bf16(af[m], bfr[n], acc[m][n], 0, 0, 0);
    __syncthreads();   // protect LDS before next stage
  }

  // epilogue: C/D layout col=lane&15, row=(lane>>4)*4+reg
  #pragma unroll
  for (int n = 0; n < 4; ++n) {
    const int col = n0 + wc * 64 + n * 16 + (lane & 15);
    const float ba = badd[col];
    #pragma unroll
    for (int m = 0; m < 4; ++m) {
      const int rbase = m0 + wr * 64 + m * 16 + ((lane >> 4) * 4);
      #pragma unroll
      for (int r = 0; r < 4; ++r)
        out[(size_t)(rbase + r) * N_DIM + col] = (acc[m][n][r] + ba) * s;
    }
  }
}

extern "C" void kernel_launch(void* const* d_in, const int* in_sizes, int n_in,
                              void* d_out, int out_size, void* d_ws, size_t ws_size,
                              hipStream_t stream) {
  const float* x = (const float*)d_in[0];
  const float* w = (const float*)d_in[1];
  float* out = (float*)d_out;
  char* ws = (char*)d_ws;
  unsigned* u = (unsigned*)ws;
  float* sc = (float*)ws + 2;
  float* bias = (float*)(ws + OFF_BIAS);
  float* badd = (float*)(ws + OFF_BADD);
  unsigned short* xq = (unsigned short*)(ws + OFF_XQ);
  unsigned short* wqT = (unsigned short*)(ws + OFF_WQT);

  hipLaunchKernelGGL(k_init, dim3(1), dim3(64), 0, stream, u);
  hipLaunchKernelGGL(k_maxx, dim3(128), dim3(256), 0, stream, x, u);
  hipLaunchKernelGGL(k_wstats, dim3(N_DIM / 64), dim3(256), 0, stream, w, bias, u);
  hipLaunchKernelGGL(k_scales, dim3(1), dim3(256), 0, stream, bias, sc, u);
  hipLaunchKernelGGL(k_badd, dim3(N_DIM / 256), dim3(256), 0, stream, bias, badd, sc);
  hipLaunchKernelGGL(k_qx, dim3(B_DIM * D_DIM / 4 / 256), dim3(256), 0, stream, x, xq, sc);
  hipLaunchKernelGGL(k_qwT, dim3(N_DIM / 64, D_DIM / 64), dim3(256), 0, stream, w, wqT, sc);
  hipLaunchKernelGGL(k_gemm, dim3(N_DIM / BN, B_DIM / BM), dim3(256), 0, stream,
                     xq, wqT, badd, sc, out);
}

// Round 2
// 53.789 us; speedup vs baseline: 1.5256x; 1.5256x over previous
//
#include <hip/hip_runtime.h>
#include <hip/hip_bf16.h>

// Problem constants (setup_inputs): x[1024][512] f32, weight[512][16384] f32, L=32
#define B_DIM 1024
#define D_DIM 512
#define N_DIM 16384

typedef __attribute__((ext_vector_type(8))) short bf16x8;
typedef __attribute__((ext_vector_type(4))) float f32x4;

// ws layout (bytes):
//   0       : f32 sc[4] = { sx, st, s=sx*st, q1=rint(1/sx) }
//   64      : f32 xpart[128]   per-block max|x|
//   1024    : f32 wpart[256]   per-block max(|w|, bias)
//   4096    : f32 bias[N]      (64 KiB)  bias[n] = sum_k w[k][n]^2 / 32
//   69632   : bf16 xq[B][D]    (1 MiB)
//   1118208 : bf16 wqT[N][D]   (16 MiB)
#define OFF_XPART 64
#define OFF_WPART 1024
#define OFF_BIAS  4096
#define OFF_XQ    69632
#define OFF_WQT   1118208

#define XMAX_BLOCKS 128
#define WSTAT_BLOCKS 256
#define QX_BLOCKS 512   // B*D/4/256

__device__ inline void gload16(const void* g, void* l) {
  __builtin_amdgcn_global_load_lds((const __attribute__((address_space(1))) void*)g,
                                   (__attribute__((address_space(3))) void*)l, 16, 0, 0);
}

__device__ inline unsigned short f2bf(float f) {
  // values here are integers |v| <= 127 -> low 16 bits of f32 are zero -> exact
  return (unsigned short)(__float_as_uint(f) >> 16);
}

// blocks [0,128): per-block max|x| -> xpart
// blocks [128,384): 64 cols each: bias[col] = sum w^2/32; wpart = max(|w|, bias)
__global__ __launch_bounds__(256) void k_stats(const float* __restrict__ x,
                                               const float* __restrict__ w,
                                               float* __restrict__ ws_f) {
  const int t = threadIdx.x;
  if (blockIdx.x < XMAX_BLOCKS) {
    __shared__ float red[256];
    float m = 0.f;
    const float4* x4 = (const float4*)x;
    const int n4 = B_DIM * D_DIM / 4;
    for (int i = blockIdx.x * 256 + t; i < n4; i += XMAX_BLOCKS * 256) {
      float4 v = x4[i];
      m = fmaxf(m, fmaxf(fmaxf(fabsf(v.x), fabsf(v.y)), fmaxf(fabsf(v.z), fabsf(v.w))));
    }
    red[t] = m; __syncthreads();
    for (int s = 128; s > 0; s >>= 1) { if (t < s) red[t] = fmaxf(red[t], red[t + s]); __syncthreads(); }
    if (t == 0) ws_f[OFF_XPART / 4 + blockIdx.x] = red[0];
  } else {
    __shared__ float sred[256], mred[256];
    const int b = blockIdx.x - XMAX_BLOCKS;
    const int c = t & 63, part = t >> 6;
    const int col = b * 64 + c;
    float ss = 0.f, mx = 0.f;
    const float* p = w + (size_t)part * 128 * N_DIM + col;
    #pragma unroll 8
    for (int d = 0; d < 128; ++d) {
      float v = p[(size_t)d * N_DIM];
      ss += v * v;
      mx = fmaxf(mx, fabsf(v));
    }
    sred[t] = ss; mred[t] = mx;
    __syncthreads();
    if (t < 64) {
      float bsum = (sred[t] + sred[t + 64] + sred[t + 128] + sred[t + 192]) * (1.0f / 32.0f);
      ws_f[OFF_BIAS / 4 + col] = bsum;
      mred[t] = fmaxf(mred[t], bsum);   // bias >= 0; ref scale = max over concat(w, bias rows)
    }
    __syncthreads();
    for (int s = 128; s > 0; s >>= 1) { if (t < s) mred[t] = fmaxf(mred[t], mred[t + s]); __syncthreads(); }
    if (t == 0) ws_f[OFF_WPART / 4 + b] = mred[0];
  }
}

// reduce 384 partials -> scales
__global__ __launch_bounds__(256) void k_scales(float* __restrict__ ws_f) {
  __shared__ float xr[256], wr[256];
  const int t = threadIdx.x;
  xr[t] = (t < XMAX_BLOCKS) ? ws_f[OFF_XPART / 4 + t] : 0.f;
  wr[t] = ws_f[OFF_WPART / 4 + t];
  __syncthreads();
  for (int s = 128; s > 0; s >>= 1) {
    if (t < s) { xr[t] = fmaxf(xr[t], xr[t + s]); wr[t] = fmaxf(wr[t], wr[t + s]); }
    __syncthreads();
  }
  if (t == 0) {
    float st = fmaxf(wr[0] / 127.0f, 1e-12f);
    float sx = fmaxf(fmaxf(xr[0], 1.0f) / 127.0f, 1e-12f);   // x padded with ones
    ws_f[0] = sx; ws_f[1] = st; ws_f[2] = sx * st; ws_f[3] = rintf(1.0f / sx);
  }
}

// blocks [0,512): quantize x -> xq bf16
// blocks [512,2560): quantize + transpose w -> wqT[n][k] bf16
__global__ __launch_bounds__(256) void k_quant(const float* __restrict__ x,
                                               const float* __restrict__ w,
                                               const float* __restrict__ sc,
                                               unsigned short* __restrict__ xq,
                                               unsigned short* __restrict__ wqT) {
  const int t = threadIdx.x;
  if (blockIdx.x < QX_BLOCKS) {
    const int i = blockIdx.x * 256 + t;   // one float4 per thread
    const float sx = sc[0];
    float4 v = ((const float4*)x)[i];
    ushort4 o;
    o.x = f2bf(rintf(v.x / sx));
    o.y = f2bf(rintf(v.y / sx));
    o.z = f2bf(rintf(v.z / sx));
    o.w = f2bf(rintf(v.w / sx));
    ((ushort4*)xq)[i] = o;
  } else {
    __shared__ float tile[64][65];
    const int bid = blockIdx.x - QX_BLOCKS;
    const int n0 = (bid & 255) * 64, k0 = (bid >> 8) * 64;
    const float st = sc[1];
    {
      const int tx = t & 63, ty = t >> 6;
      #pragma unroll
      for (int i = 0; i < 16; ++i) {
        int r = i * 4 + ty;
        tile[r][tx] = w[(size_t)(k0 + r) * N_DIM + n0 + tx];
      }
    }
    __syncthreads();
    // write: thread -> (k-group kg of 4, n-row nl); LDS reads 2-way aliased (free)
    const int kg = t & 15, nr = t >> 4;
    #pragma unroll
    for (int it = 0; it < 4; ++it) {
      const int nl = it * 16 + nr;
      ushort4 o;
      o.x = f2bf(rintf(tile[kg * 4 + 0][nl] / st));
      o.y = f2bf(rintf(tile[kg * 4 + 1][nl] / st));
      o.z = f2bf(rintf(tile[kg * 4 + 2][nl] / st));
      o.w = f2bf(rintf(tile[kg * 4 + 3][nl] / st));
      *(ushort4*)&wqT[(size_t)(n0 + nl) * D_DIM + k0 + kg * 4] = o;
    }
  }
}

// GEMM: out[b][n] = (sum_k xq[b][k]*wqT[n][k] + 32*q1*rint(bias[n]/st)) * s
// m97 structure: 128x128 tile, BK=32, 4 waves (2x2), 16x16x32 bf16 MFMA,
// global_load_lds width-16 staging, 2 barriers per K-step.
#define BM 128
#define BN 128
#define BK 32

__global__ __launch_bounds__(256) void k_gemm(const unsigned short* __restrict__ xq,
                                              const unsigned short* __restrict__ wqT,
                                              const float* __restrict__ bias,
                                              const float* __restrict__ sc,
                                              float* __restrict__ out) {
  __shared__ __align__(16) short lds_a[BM * BK];  // [128 m][32 k] bf16
  __shared__ __align__(16) short lds_b[BN * BK];  // [128 n][32 k]
  const int t = threadIdx.x;
  const int lane = t & 63, w = t >> 6;
  const int wr = w >> 1, wc = w & 1;
  const int n0 = blockIdx.x * BN, m0 = blockIdx.y * BM;

  f32x4 acc[4][4] = {};
  const float st = sc[1], s = sc[2], q1 = sc[3];

  for (int kt = 0; kt < D_DIM / BK; ++kt) {
    const int k0 = kt * BK;
    // stage A and B tiles: per issue, 256 threads x 16B = 4096B (64 rows)
    #pragma unroll
    for (int i = 0; i < 2; ++i) {
      const int row = i * 64 + (t >> 2);
      const int ko = (t & 3) * 8;
      gload16(xq + (size_t)(m0 + row) * D_DIM + k0 + ko, &lds_a[i * 2048 + w * 512]);
      gload16(wqT + (size_t)(n0 + row) * D_DIM + k0 + ko, &lds_b[i * 2048 + w * 512]);
    }
    __syncthreads();   // drains vmcnt: LDS tiles complete

    bf16x8 af[4], bfr[4];
    #pragma unroll
    for (int m = 0; m < 4; ++m) {
      const int row = wr * 64 + m * 16 + (lane & 15);
      af[m] = *(const bf16x8*)&lds_a[row * BK + (lane >> 4) * 8];
    }
    #pragma unroll
    for (int n = 0; n < 4; ++n) {
      const int row = wc * 64 + n * 16 + (lane & 15);
      bfr[n] = *(const bf16x8*)&lds_b[row * BK + (lane >> 4) * 8];
    }
    #pragma unroll
    for (int m = 0; m < 4; ++m)
      #pragma unroll
      for (int n = 0; n < 4; ++n)
        acc[m][n] = __builtin_amdgcn_mfma_f32_16x16x32_bf16(af[m], bfr[n], acc[m][n], 0, 0, 0);
    __syncthreads();   // protect LDS before next stage
  }

  // epilogue: C/D layout col=lane&15, row=(lane>>4)*4+reg; bias term folded in
  #pragma unroll
  for (int n = 0; n < 4; ++n) {
    const int col = n0 + wc * 64 + n * 16 + (lane & 15);
    const float ba = 32.0f * q1 * rintf(bias[col] / st);
    #pragma unroll
    for (int m = 0; m < 4; ++m) {
      const int rbase = m0 + wr * 64 + m * 16 + ((lane >> 4) * 4);
      #pragma unroll
      for (int r = 0; r < 4; ++r)
        out[(size_t)(rbase + r) * N_DIM + col] = (acc[m][n][r] + ba) * s;
    }
  }
}

extern "C" void kernel_launch(void* const* d_in, const int* in_sizes, int n_in,
                              void* d_out, int out_size, void* d_ws, size_t ws_size,
                              hipStream_t stream) {
  const float* x = (const float*)d_in[0];
  const float* w = (const float*)d_in[1];
  float* out = (float*)d_out;
  char* ws = (char*)d_ws;
  float* ws_f = (float*)ws;
  const float* sc = (const float*)ws;
  float* bias = (float*)(ws + OFF_BIAS);
  unsigned short* xq = (unsigned short*)(ws + OFF_XQ);
  unsigned short* wqT = (unsigned short*)(ws + OFF_WQT);

  hipLaunchKernelGGL(k_stats, dim3(XMAX_BLOCKS + WSTAT_BLOCKS), dim3(256), 0, stream, x, w, ws_f);
  hipLaunchKernelGGL(k_scales, dim3(1), dim3(256), 0, stream, ws_f);
  hipLaunchKernelGGL(k_quant, dim3(QX_BLOCKS + 2048), dim3(256), 0, stream, x, w, sc, xq, wqT);
  hipLaunchKernelGGL(k_gemm, dim3(N_DIM / BN, B_DIM / BM), dim3(256), 0, stream,
                     xq, wqT, bias, sc, out);
}

// Round 3
// 48.189 us; speedup vs baseline: 1.7029x; 1.1162x over previous
//
#include <hip/hip_runtime.h>
#include <hip/hip_bf16.h>

// Problem constants (setup_inputs): x[1024][512] f32, weight[512][16384] f32, L=32
#define B_DIM 1024
#define D_DIM 512
#define N_DIM 16384

typedef __attribute__((ext_vector_type(8))) short bf16x8;
typedef __attribute__((ext_vector_type(4))) float f32x4;

// ws layout (bytes):
//   64      : f32 xpart[128]   per-block max|x|          (f32 idx 16)
//   1024    : f32 wpart[256]   per-block max(|w|, bias)  (f32 idx 256)
//   4096    : f32 bias[N]      (64 KiB)  bias[n] = sum_k w[k][n]^2 / 32
//   69632   : bf16 xq[B][D]    (1 MiB)
//   1118208 : bf16 wqT[N][D]   (16 MiB)
#define IDX_XPART 16
#define IDX_WPART 256
#define OFF_BIAS  4096
#define OFF_XQ    69632
#define OFF_WQT   1118208

#define XMAX_BLOCKS 128
#define WSTAT_BLOCKS 256
#define QX_BLOCKS 512   // B*D/4/256

__device__ inline void gload16(const void* g, void* l) {
  __builtin_amdgcn_global_load_lds((const __attribute__((address_space(1))) void*)g,
                                   (__attribute__((address_space(3))) void*)l, 16, 0, 0);
}

__device__ inline unsigned short f2bf(float f) {
  // values here are integers |v| <= 127 -> low 16 bits of f32 are zero -> exact
  return (unsigned short)(__float_as_uint(f) >> 16);
}

// Every lane computes all scales from the 384 partials (fmax is exact -> any
// reduction order is bit-identical to any other).
__device__ inline void compute_scales(const float* __restrict__ ws_f, int lane,
                                      float& sx, float& st, float& s, float& q1) {
  float xm = fmaxf(ws_f[IDX_XPART + lane], ws_f[IDX_XPART + 64 + lane]);
  float wm = fmaxf(fmaxf(ws_f[IDX_WPART + lane], ws_f[IDX_WPART + 64 + lane]),
                   fmaxf(ws_f[IDX_WPART + 128 + lane], ws_f[IDX_WPART + 192 + lane]));
  #pragma unroll
  for (int i = 1; i < 64; i <<= 1) {
    xm = fmaxf(xm, __shfl_xor(xm, i, 64));
    wm = fmaxf(wm, __shfl_xor(wm, i, 64));
  }
  st = fmaxf(wm / 127.0f, 1e-12f);
  sx = fmaxf(fmaxf(xm, 1.0f) / 127.0f, 1e-12f);   // x padded with ones
  s = sx * st;
  q1 = rintf(1.0f / sx);
}

// blocks [0,128): per-block max|x| -> xpart
// blocks [128,384): 64 cols each: bias[col] = sum w^2/32; wpart = max(|w|, bias)
__global__ __launch_bounds__(256) void k_stats(const float* __restrict__ x,
                                               const float* __restrict__ w,
                                               float* __restrict__ ws_f) {
  const int t = threadIdx.x;
  if (blockIdx.x < XMAX_BLOCKS) {
    __shared__ float red[256];
    float m = 0.f;
    const float4* x4 = (const float4*)x;
    const int n4 = B_DIM * D_DIM / 4;
    for (int i = blockIdx.x * 256 + t; i < n4; i += XMAX_BLOCKS * 256) {
      float4 v = x4[i];
      m = fmaxf(m, fmaxf(fmaxf(fabsf(v.x), fabsf(v.y)), fmaxf(fabsf(v.z), fabsf(v.w))));
    }
    red[t] = m; __syncthreads();
    for (int s = 128; s > 0; s >>= 1) { if (t < s) red[t] = fmaxf(red[t], red[t + s]); __syncthreads(); }
    if (t == 0) ws_f[IDX_XPART + blockIdx.x] = red[0];
  } else {
    __shared__ float sred[256], mred[256];
    const int b = blockIdx.x - XMAX_BLOCKS;
    const int c = t & 63, part = t >> 6;
    const int col = b * 64 + c;
    float ss = 0.f, mx = 0.f;
    const float* p = w + (size_t)part * 128 * N_DIM + col;
    #pragma unroll 8
    for (int d = 0; d < 128; ++d) {
      float v = p[(size_t)d * N_DIM];
      ss += v * v;
      mx = fmaxf(mx, fabsf(v));
    }
    sred[t] = ss; mred[t] = mx;
    __syncthreads();
    if (t < 64) {
      float bsum = (sred[t] + sred[t + 64] + sred[t + 128] + sred[t + 192]) * (1.0f / 32.0f);
      ws_f[OFF_BIAS / 4 + col] = bsum;
      mred[t] = fmaxf(mred[t], bsum);   // bias >= 0; ref scale = max over concat(w, bias rows)
    }
    __syncthreads();
    for (int s = 128; s > 0; s >>= 1) { if (t < s) mred[t] = fmaxf(mred[t], mred[t + s]); __syncthreads(); }
    if (t == 0) ws_f[IDX_WPART + b] = mred[0];
  }
}

// blocks [0,512): quantize x -> xq bf16
// blocks [512,2560): quantize + transpose w -> wqT[n][k] bf16
__global__ __launch_bounds__(256) void k_quant(const float* __restrict__ x,
                                               const float* __restrict__ w,
                                               const float* __restrict__ ws_f,
                                               unsigned short* __restrict__ xq,
                                               unsigned short* __restrict__ wqT) {
  const int t = threadIdx.x;
  float sx, st, s_u, q1_u;
  compute_scales(ws_f, t & 63, sx, st, s_u, q1_u);
  if (blockIdx.x < QX_BLOCKS) {
    const int i = blockIdx.x * 256 + t;   // one float4 per thread
    float4 v = ((const float4*)x)[i];
    ushort4 o;
    o.x = f2bf(rintf(v.x / sx));
    o.y = f2bf(rintf(v.y / sx));
    o.z = f2bf(rintf(v.z / sx));
    o.w = f2bf(rintf(v.w / sx));
    ((ushort4*)xq)[i] = o;
  } else {
    __shared__ float tile[64][65];
    const int bid = blockIdx.x - QX_BLOCKS;
    const int n0 = (bid & 255) * 64, k0 = (bid >> 8) * 64;
    {
      const int tx = t & 63, ty = t >> 6;
      #pragma unroll
      for (int i = 0; i < 16; ++i) {
        int r = i * 4 + ty;
        tile[r][tx] = w[(size_t)(k0 + r) * N_DIM + n0 + tx];
      }
    }
    __syncthreads();
    // write: thread -> (k-group kg of 4, n-row nl); LDS reads 2-way aliased (free)
    const int kg = t & 15, nr = t >> 4;
    #pragma unroll
    for (int it = 0; it < 4; ++it) {
      const int nl = it * 16 + nr;
      ushort4 o;
      o.x = f2bf(rintf(tile[kg * 4 + 0][nl] / st));
      o.y = f2bf(rintf(tile[kg * 4 + 1][nl] / st));
      o.z = f2bf(rintf(tile[kg * 4 + 2][nl] / st));
      o.w = f2bf(rintf(tile[kg * 4 + 3][nl] / st));
      *(ushort4*)&wqT[(size_t)(n0 + nl) * D_DIM + k0 + kg * 4] = o;
    }
  }
}

// ---------------- GEMM: 256x256 tile, BK=64, 8 waves (2M x 4N), phased dbuf ----------------
// out[b][n] = (sum_k xq[b][k]*wqT[n][k] + 32*q1*rint(bias[n]/st)) * s
// LDS: 2 buffers x (A[256][64] + B[256][64]) bf16 = 128 KiB, XOR-swizzled chunks.
// Per K-tile: 4 phases (C-quadrants); each phase issues 2 prefetch halves of tile T+1
// into the OTHER buffer; single vmcnt(0) drain per K-tile at phase 3.

// stage 8 rows (1024B) of a 256-row tile: linear LDS dest, inverse-swizzled global src.
// LDS[r][c] holds global k-chunk c ^ (r&7)  (chunks of 8 bf16 = 16B).
__device__ inline void stage8(const unsigned short* __restrict__ g, int grow0, int kbase,
                              short* ldst, int w, int lane, int issue) {
  const int r0 = w * 32 + issue * 8;
  const int rl = r0 + (lane >> 3);
  const int kc = (lane & 7) ^ (lane >> 3);
  gload16(g + (size_t)(grow0 + rl) * D_DIM + kbase + kc * 8, ldst + r0 * 64);
}

__global__ __launch_bounds__(512, 2) void k_gemm(const unsigned short* __restrict__ xq,
                                                 const unsigned short* __restrict__ wqT,
                                                 const float* __restrict__ bias,
                                                 const float* __restrict__ ws_f,
                                                 float* __restrict__ out) {
  __shared__ __align__(16) short lds[2 * 32768];   // [buf][A 16384 | B 16384] shorts
  const int t = threadIdx.x;
  const int lane = t & 63, w = t >> 6;
  const int wm = w >> 2, wn = w & 3;               // 2 x 4 wave grid
  const int m0 = blockIdx.y * 256, n0 = blockIdx.x * 256;

  // prologue: stage tile 0 into buf 0 (8 issues/wave), scales reduce under the loads
  #pragma unroll
  for (int i = 0; i < 4; ++i) {
    stage8(xq, m0, 0, &lds[0], w, lane, i);
    stage8(wqT, n0, 0, &lds[16384], w, lane, i);
  }
  float sx_u, st, s, q1;
  compute_scales(ws_f, lane, sx_u, st, s, q1);

  f32x4 acc[8][4] = {};

  asm volatile("s_waitcnt vmcnt(0)" ::: "memory");
  __builtin_amdgcn_s_barrier();
  __builtin_amdgcn_sched_barrier(0);

  for (int T = 0; T < 8; ++T) {
    short* bufA = &lds[(T & 1) * 32768];
    short* bufB = bufA + 16384;
    short* nA = &lds[((T + 1) & 1) * 32768];
    short* nB = nA + 16384;
    bf16x8 bfr[4][2];
    #pragma unroll
    for (int q = 0; q < 4; ++q) {
      if (q == 0) {
        #pragma unroll
        for (int fn = 0; fn < 4; ++fn)
          #pragma unroll
          for (int ks = 0; ks < 2; ++ks) {
            const int row = wn * 64 + fn * 16 + (lane & 15);
            const int cp = (ks * 4 + (lane >> 4)) ^ (lane & 7);
            bfr[fn][ks] = *(const bf16x8*)&bufB[row * 64 + cp * 8];
          }
      }
      bf16x8 af[2][2];
      #pragma unroll
      for (int fm = 0; fm < 2; ++fm)
        #pragma unroll
        for (int ks = 0; ks < 2; ++ks) {
          const int row = wm * 128 + (q * 2 + fm) * 16 + (lane & 15);
          const int cp = (ks * 4 + (lane >> 4)) ^ (lane & 7);
          af[fm][ks] = *(const bf16x8*)&bufA[row * 64 + cp * 8];
        }
      if (T < 7) {                       // prefetch 2 halves of tile T+1 -> other buffer
        stage8(xq, m0, (T + 1) * 64, nA, w, lane, q);
        stage8(wqT, n0, (T + 1) * 64, nB, w, lane, q);
      }
      __builtin_amdgcn_s_barrier();      // pace phases (no vm/lgkm drain)
      __builtin_amdgcn_s_setprio(1);
      #pragma unroll
      for (int fm = 0; fm < 2; ++fm)
        #pragma unroll
        for (int ks = 0; ks < 2; ++ks)
          #pragma unroll
          for (int fn = 0; fn < 4; ++fn)
            acc[q * 2 + fm][fn] = __builtin_amdgcn_mfma_f32_16x16x32_bf16(
                af[fm][ks], bfr[fn][ks], acc[q * 2 + fm][fn], 0, 0, 0);
      __builtin_amdgcn_s_setprio(0);
      if (q == 3) asm volatile("s_waitcnt vmcnt(0)" ::: "memory");  // tile-boundary drain
      __builtin_amdgcn_s_barrier();
    }
    __builtin_amdgcn_sched_barrier(0);   // nothing crosses the tile boundary
  }

  // epilogue: C/D layout col=lane&15, row=(lane>>4)*4+reg; bias term folded in
  #pragma unroll
  for (int fn = 0; fn < 4; ++fn) {
    const int col = n0 + wn * 64 + fn * 16 + (lane & 15);
    const float ba = 32.0f * q1 * rintf(bias[col] / st);
    #pragma unroll
    for (int fm = 0; fm < 8; ++fm) {
      const int rbase = m0 + wm * 128 + fm * 16 + ((lane >> 4) * 4);
      #pragma unroll
      for (int r = 0; r < 4; ++r)
        out[(size_t)(rbase + r) * N_DIM + col] = (acc[fm][fn][r] + ba) * s;
    }
  }
}

extern "C" void kernel_launch(void* const* d_in, const int* in_sizes, int n_in,
                              void* d_out, int out_size, void* d_ws, size_t ws_size,
                              hipStream_t stream) {
  const float* x = (const float*)d_in[0];
  const float* w = (const float*)d_in[1];
  float* out = (float*)d_out;
  char* ws = (char*)d_ws;
  float* ws_f = (float*)ws;
  float* bias = (float*)(ws + OFF_BIAS);
  unsigned short* xq = (unsigned short*)(ws + OFF_XQ);
  unsigned short* wqT = (unsigned short*)(ws + OFF_WQT);

  hipLaunchKernelGGL(k_stats, dim3(XMAX_BLOCKS + WSTAT_BLOCKS), dim3(256), 0, stream, x, w, ws_f);
  hipLaunchKernelGGL(k_quant, dim3(QX_BLOCKS + 2048), dim3(256), 0, stream, x, w, ws_f, xq, wqT);
  hipLaunchKernelGGL(k_gemm, dim3(N_DIM / 256, B_DIM / 256), dim3(512), 0, stream,
                     xq, wqT, bias, ws_f, out);
}

// Round 4
// 46.795 us; speedup vs baseline: 1.7536x; 1.0298x over previous
//
#include <hip/hip_runtime.h>
#include <hip/hip_bf16.h>

// Problem constants (setup_inputs): x[1024][512] f32, weight[512][16384] f32, L=32
#define B_DIM 1024
#define D_DIM 512
#define N_DIM 16384

typedef __attribute__((ext_vector_type(8))) short bf16x8;
typedef __attribute__((ext_vector_type(4))) float f32x4;

// ws layout (bytes):
//   64      : f32 xpart[128]   per-block max|x|          (f32 idx 16)
//   1024    : f32 wpart[256]   per-block max(|w|, bias)  (f32 idx 256)
//   4096    : f32 bias[N]      (64 KiB)  bias[n] = sum_k w[k][n]^2 / 32
//   69632   : bf16 xq[B][D]    (1 MiB)
//   1118208 : bf16 wqT[N][D]   (16 MiB)
#define IDX_XPART 16
#define IDX_WPART 256
#define OFF_BIAS  4096
#define OFF_XQ    69632
#define OFF_WQT   1118208

#define XMAX_BLOCKS 128
#define WSTAT_BLOCKS 256
#define QX_BLOCKS 512   // B*D/4/256

__device__ inline void gload16(const void* g, void* l) {
  __builtin_amdgcn_global_load_lds((const __attribute__((address_space(1))) void*)g,
                                   (__attribute__((address_space(3))) void*)l, 16, 0, 0);
}

__device__ inline unsigned short f2bf(float f) {
  // values here are integers |v| <= 127 -> low 16 bits of f32 are zero -> exact
  return (unsigned short)(__float_as_uint(f) >> 16);
}

// Every lane computes all scales from the 384 partials (fmax is exact -> any
// reduction order is bit-identical to any other).
__device__ inline void compute_scales(const float* __restrict__ ws_f, int lane,
                                      float& sx, float& st, float& s, float& q1) {
  float xm = fmaxf(ws_f[IDX_XPART + lane], ws_f[IDX_XPART + 64 + lane]);
  float wm = fmaxf(fmaxf(ws_f[IDX_WPART + lane], ws_f[IDX_WPART + 64 + lane]),
                   fmaxf(ws_f[IDX_WPART + 128 + lane], ws_f[IDX_WPART + 192 + lane]));
  #pragma unroll
  for (int i = 1; i < 64; i <<= 1) {
    xm = fmaxf(xm, __shfl_xor(xm, i, 64));
    wm = fmaxf(wm, __shfl_xor(wm, i, 64));
  }
  st = fmaxf(wm / 127.0f, 1e-12f);
  sx = fmaxf(fmaxf(xm, 1.0f) / 127.0f, 1e-12f);   // x padded with ones
  s = sx * st;
  q1 = rintf(1.0f / sx);
}

// blocks [0,128): per-block max|x| -> xpart
// blocks [128,384): 64 cols each: bias[col] = sum w^2/32; wpart = max(|w|, bias)
__global__ __launch_bounds__(256) void k_stats(const float* __restrict__ x,
                                               const float* __restrict__ w,
                                               float* __restrict__ ws_f) {
  const int t = threadIdx.x;
  if (blockIdx.x < XMAX_BLOCKS) {
    __shared__ float red[256];
    float m = 0.f;
    const float4* x4 = (const float4*)x;
    const int n4 = B_DIM * D_DIM / 4;
    for (int i = blockIdx.x * 256 + t; i < n4; i += XMAX_BLOCKS * 256) {
      float4 v = x4[i];
      m = fmaxf(m, fmaxf(fmaxf(fabsf(v.x), fabsf(v.y)), fmaxf(fabsf(v.z), fabsf(v.w))));
    }
    red[t] = m; __syncthreads();
    for (int s = 128; s > 0; s >>= 1) { if (t < s) red[t] = fmaxf(red[t], red[t + s]); __syncthreads(); }
    if (t == 0) ws_f[IDX_XPART + blockIdx.x] = red[0];
  } else {
    __shared__ float sred[256], mred[256];
    const int b = blockIdx.x - XMAX_BLOCKS;
    const int c = t & 63, part = t >> 6;
    const int col = b * 64 + c;
    float ss = 0.f, mx = 0.f;
    const float* p = w + (size_t)part * 128 * N_DIM + col;
    #pragma unroll 8
    for (int d = 0; d < 128; ++d) {
      float v = p[(size_t)d * N_DIM];
      ss += v * v;
      mx = fmaxf(mx, fabsf(v));
    }
    sred[t] = ss; mred[t] = mx;
    __syncthreads();
    if (t < 64) {
      float bsum = (sred[t] + sred[t + 64] + sred[t + 128] + sred[t + 192]) * (1.0f / 32.0f);
      ws_f[OFF_BIAS / 4 + col] = bsum;
      mred[t] = fmaxf(mred[t], bsum);   // bias >= 0; ref scale = max over concat(w, bias rows)
    }
    __syncthreads();
    for (int s = 128; s > 0; s >>= 1) { if (t < s) mred[t] = fmaxf(mred[t], mred[t + s]); __syncthreads(); }
    if (t == 0) ws_f[IDX_WPART + b] = mred[0];
  }
}

// blocks [0,512): quantize x -> xq bf16
// blocks [512,2560): quantize + transpose w -> wqT[n][k] bf16
__global__ __launch_bounds__(256) void k_quant(const float* __restrict__ x,
                                               const float* __restrict__ w,
                                               const float* __restrict__ ws_f,
                                               unsigned short* __restrict__ xq,
                                               unsigned short* __restrict__ wqT) {
  const int t = threadIdx.x;
  float sx, st, s_u, q1_u;
  compute_scales(ws_f, t & 63, sx, st, s_u, q1_u);
  if (blockIdx.x < QX_BLOCKS) {
    const int i = blockIdx.x * 256 + t;   // one float4 per thread
    float4 v = ((const float4*)x)[i];
    ushort4 o;
    o.x = f2bf(rintf(v.x / sx));
    o.y = f2bf(rintf(v.y / sx));
    o.z = f2bf(rintf(v.z / sx));
    o.w = f2bf(rintf(v.w / sx));
    ((ushort4*)xq)[i] = o;
  } else {
    __shared__ float tile[64][65];
    const int bid = blockIdx.x - QX_BLOCKS;
    const int n0 = (bid & 255) * 64, k0 = (bid >> 8) * 64;
    {
      const int tx = t & 63, ty = t >> 6;
      #pragma unroll
      for (int i = 0; i < 16; ++i) {
        int r = i * 4 + ty;
        tile[r][tx] = w[(size_t)(k0 + r) * N_DIM + n0 + tx];
      }
    }
    __syncthreads();
    // write: thread -> (k-group kg of 4, n-row nl); LDS reads 2-way aliased (free)
    const int kg = t & 15, nr = t >> 4;
    #pragma unroll
    for (int it = 0; it < 4; ++it) {
      const int nl = it * 16 + nr;
      ushort4 o;
      o.x = f2bf(rintf(tile[kg * 4 + 0][nl] / st));
      o.y = f2bf(rintf(tile[kg * 4 + 1][nl] / st));
      o.z = f2bf(rintf(tile[kg * 4 + 2][nl] / st));
      o.w = f2bf(rintf(tile[kg * 4 + 3][nl] / st));
      *(ushort4*)&wqT[(size_t)(n0 + nl) * D_DIM + k0 + kg * 4] = o;
    }
  }
}

// ---------------- GEMM: 128x128 tile, BK=32, 4 waves (2x2), 3-buffer prefetch-2 ----------------
// out[b][n] = (sum_k xq[b][k]*wqT[n][k] + 32*q1*rint(bias[n]/st)) * s
// LDS: 3 buffers x (A[128][32] + B[128][32]) bf16 = 48 KiB -> 3 blocks/CU.
// Counted vmcnt(4) at tile boundaries (T+2's loads stay in flight); 1 barrier/tile.
// Chunk swizzle: LDS[r][c] holds global k-chunk c ^ (r&3) (chunks of 8 bf16 = 16B).
#define NT 16   // 512 / 32

// stage one tile's A+B quarter per wave: 2 issues each (16 rows / issue)
__device__ inline void stage4(const unsigned short* __restrict__ xq,
                              const unsigned short* __restrict__ wqT,
                              int m0, int n0, int kbase, short* buf, int w, int lane) {
  #pragma unroll
  for (int i = 0; i < 2; ++i) {
    const int r0 = w * 32 + i * 16;
    const int rl = r0 + (lane >> 2);
    const int kc = (lane & 3) ^ ((lane >> 2) & 3);
    gload16(xq + (size_t)(m0 + rl) * D_DIM + kbase + kc * 8, buf + r0 * 32);
    gload16(wqT + (size_t)(n0 + rl) * D_DIM + kbase + kc * 8, buf + 4096 + r0 * 32);
  }
}

__global__ __launch_bounds__(256, 3) void k_gemm(const unsigned short* __restrict__ xq,
                                                 const unsigned short* __restrict__ wqT,
                                                 const float* __restrict__ bias,
                                                 const float* __restrict__ ws_f,
                                                 float* __restrict__ out) {
  __shared__ __align__(16) short lds[3 * 8192];   // buf b: A at b*8192, B at +4096
  const int t = threadIdx.x;
  const int lane = t & 63, w = t >> 6;
  const int wm = w >> 1, wn = w & 1;
  // XCD-chunked swizzle: each XCD gets 16 consecutive n-panels x all 8 m-panels;
  // within a chunk the 8 sharers of a wqT panel are consecutive -> L2 reuse.
  const int nid = (blockIdx.x & 7) * 128 + (blockIdx.x >> 3);
  const int m0 = (nid & 7) * 128;
  const int n0 = (nid >> 3) * 128;

  // prologue: stage tiles 0,1; scales reduce under the loads
  stage4(xq, wqT, m0, n0, 0, &lds[0], w, lane);
  stage4(xq, wqT, m0, n0, 32, &lds[8192], w, lane);
  float sx_u, st, s, q1;
  compute_scales(ws_f, lane, sx_u, st, s, q1);

  f32x4 acc[4][4] = {};

  asm volatile("s_waitcnt vmcnt(4)" ::: "memory");   // tile 0 landed; tile 1 in flight
  __builtin_amdgcn_s_barrier();
  __builtin_amdgcn_sched_barrier(0);

  for (int T = 0; T < NT; ++T) {
    short* buf = &lds[(T % 3) * 8192];
    bf16x8 af[4], bfr[4];
    #pragma unroll
    for (int f = 0; f < 4; ++f) {
      const int ra = wm * 64 + f * 16 + (lane & 15);
      af[f] = *(const bf16x8*)&buf[ra * 32 + (((lane >> 4) ^ (ra & 3))) * 8];
      const int rb = wn * 64 + f * 16 + (lane & 15);
      bfr[f] = *(const bf16x8*)&buf[4096 + rb * 32 + (((lane >> 4) ^ (rb & 3))) * 8];
    }
    if (T + 2 < NT)
      stage4(xq, wqT, m0, n0, (T + 2) * 32, &lds[((T + 2) % 3) * 8192], w, lane);
    __builtin_amdgcn_s_setprio(1);
    #pragma unroll
    for (int fm = 0; fm < 4; ++fm)
      #pragma unroll
      for (int fn = 0; fn < 4; ++fn)
        acc[fm][fn] = __builtin_amdgcn_mfma_f32_16x16x32_bf16(af[fm], bfr[fn], acc[fm][fn], 0, 0, 0);
    __builtin_amdgcn_s_setprio(0);
    if (T + 2 < NT)      asm volatile("s_waitcnt vmcnt(4)" ::: "memory");  // T+1 landed
    else if (T + 1 < NT) asm volatile("s_waitcnt vmcnt(0)" ::: "memory");  // tail drain
    if (T + 1 < NT) __builtin_amdgcn_s_barrier();
    __builtin_amdgcn_sched_barrier(0);
  }

  // epilogue: C/D layout col=lane&15, row=(lane>>4)*4+reg; bias term folded in
  #pragma unroll
  for (int fn = 0; fn < 4; ++fn) {
    const int col = n0 + wn * 64 + fn * 16 + (lane & 15);
    const float ba = 32.0f * q1 * rintf(bias[col] / st);
    #pragma unroll
    for (int fm = 0; fm < 4; ++fm) {
      const int rbase = m0 + wm * 64 + fm * 16 + ((lane >> 4) * 4);
      #pragma unroll
      for (int r = 0; r < 4; ++r)
        out[(size_t)(rbase + r) * N_DIM + col] = (acc[fm][fn][r] + ba) * s;
    }
  }
}

extern "C" void kernel_launch(void* const* d_in, const int* in_sizes, int n_in,
                              void* d_out, int out_size, void* d_ws, size_t ws_size,
                              hipStream_t stream) {
  const float* x = (const float*)d_in[0];
  const float* w = (const float*)d_in[1];
  float* out = (float*)d_out;
  char* ws = (char*)d_ws;
  float* ws_f = (float*)ws;
  float* bias = (float*)(ws + OFF_BIAS);
  unsigned short* xq = (unsigned short*)(ws + OFF_XQ);
  unsigned short* wqT = (unsigned short*)(ws + OFF_WQT);

  hipLaunchKernelGGL(k_stats, dim3(XMAX_BLOCKS + WSTAT_BLOCKS), dim3(256), 0, stream, x, w, ws_f);
  hipLaunchKernelGGL(k_quant, dim3(QX_BLOCKS + 2048), dim3(256), 0, stream, x, w, ws_f, xq, wqT);
  hipLaunchKernelGGL(k_gemm, dim3((B_DIM / 128) * (N_DIM / 128)), dim3(256), 0, stream,
                     xq, wqT, bias, ws_f, out);
}

// Round 5
// 41.913 us; speedup vs baseline: 1.9579x; 1.1165x over previous
//
#include <hip/hip_runtime.h>
#include <hip/hip_bf16.h>

// Problem constants (setup_inputs): x[1024][512] f32, weight[512][16384] f32, L=32
#define B_DIM 1024
#define D_DIM 512
#define N_DIM 16384

typedef __attribute__((ext_vector_type(4))) int   i32x4;
typedef __attribute__((ext_vector_type(4))) float f32x4;

// ws layout (bytes):
//   64      : f32 xpart[128]   per-block max|x|          (f32 idx 16)
//   1024    : f32 wpart[256]   per-block max(|w|, bias)  (f32 idx 256)
//   4096    : f32 bias[N]      (64 KiB)  bias[n] = sum_k w[k][n]^2 / 32
//   69632   : i8  xq[B][D]     (512 KiB)
//   593920  : i8  wqT[N][D]    (8 MiB)
#define IDX_XPART 16
#define IDX_WPART 256
#define OFF_BIAS  4096
#define OFF_XQ    69632
#define OFF_WQT   593920

#define XMAX_BLOCKS 128
#define WSTAT_BLOCKS 256
#define QX_BLOCKS 512   // B*D/4/256

__device__ inline void gload16(const void* g, void* l) {
  __builtin_amdgcn_global_load_lds((const __attribute__((address_space(1))) void*)g,
                                   (__attribute__((address_space(3))) void*)l, 16, 0, 0);
}

// Every lane computes all scales from the 384 partials (fmax is exact -> any
// reduction order is bit-identical to any other).
__device__ inline void compute_scales(const float* __restrict__ ws_f, int lane,
                                      float& sx, float& st, float& s, float& q1) {
  float xm = fmaxf(ws_f[IDX_XPART + lane], ws_f[IDX_XPART + 64 + lane]);
  float wm = fmaxf(fmaxf(ws_f[IDX_WPART + lane], ws_f[IDX_WPART + 64 + lane]),
                   fmaxf(ws_f[IDX_WPART + 128 + lane], ws_f[IDX_WPART + 192 + lane]));
  #pragma unroll
  for (int i = 1; i < 64; i <<= 1) {
    xm = fmaxf(xm, __shfl_xor(xm, i, 64));
    wm = fmaxf(wm, __shfl_xor(wm, i, 64));
  }
  st = fmaxf(wm / 127.0f, 1e-12f);
  sx = fmaxf(fmaxf(xm, 1.0f) / 127.0f, 1e-12f);   // x padded with ones
  s = sx * st;
  q1 = rintf(1.0f / sx);
}

// blocks [0,128): per-block max|x| -> xpart
// blocks [128,384): 64 cols each: bias[col] = sum w^2/32; wpart = max(|w|, bias)
__global__ __launch_bounds__(256) void k_stats(const float* __restrict__ x,
                                               const float* __restrict__ w,
                                               float* __restrict__ ws_f) {
  const int t = threadIdx.x;
  if (blockIdx.x < XMAX_BLOCKS) {
    __shared__ float red[256];
    float m = 0.f;
    const float4* x4 = (const float4*)x;
    const int n4 = B_DIM * D_DIM / 4;
    for (int i = blockIdx.x * 256 + t; i < n4; i += XMAX_BLOCKS * 256) {
      float4 v = x4[i];
      m = fmaxf(m, fmaxf(fmaxf(fabsf(v.x), fabsf(v.y)), fmaxf(fabsf(v.z), fabsf(v.w))));
    }
    red[t] = m; __syncthreads();
    for (int s = 128; s > 0; s >>= 1) { if (t < s) red[t] = fmaxf(red[t], red[t + s]); __syncthreads(); }
    if (t == 0) ws_f[IDX_XPART + blockIdx.x] = red[0];
  } else {
    __shared__ float sred[256], mred[256];
    const int b = blockIdx.x - XMAX_BLOCKS;
    const int c = t & 63, part = t >> 6;
    const int col = b * 64 + c;
    float ss = 0.f, mx = 0.f;
    const float* p = w + (size_t)part * 128 * N_DIM + col;
    #pragma unroll 8
    for (int d = 0; d < 128; ++d) {
      float v = p[(size_t)d * N_DIM];
      ss += v * v;
      mx = fmaxf(mx, fabsf(v));
    }
    sred[t] = ss; mred[t] = mx;
    __syncthreads();
    if (t < 64) {
      float bsum = (sred[t] + sred[t + 64] + sred[t + 128] + sred[t + 192]) * (1.0f / 32.0f);
      ws_f[OFF_BIAS / 4 + col] = bsum;
      mred[t] = fmaxf(mred[t], bsum);   // bias >= 0; ref scale = max over concat(w, bias rows)
    }
    __syncthreads();
    for (int s = 128; s > 0; s >>= 1) { if (t < s) mred[t] = fmaxf(mred[t], mred[t + s]); __syncthreads(); }
    if (t == 0) ws_f[IDX_WPART + b] = mred[0];
  }
}

__device__ inline unsigned pack4(float a, float b, float c, float d, float inv) {
  int q0 = (int)rintf(a * inv), q1 = (int)rintf(b * inv);
  int q2 = (int)rintf(c * inv), q3 = (int)rintf(d * inv);
  return (q0 & 255) | ((q1 & 255) << 8) | ((q2 & 255) << 16) | ((unsigned)(q3 & 255) << 24);
}

// blocks [0,512): quantize x -> xq i8
// blocks [512,2560): quantize + transpose w -> wqT[n][k] i8
__global__ __launch_bounds__(256) void k_quant(const float* __restrict__ x,
                                               const float* __restrict__ w,
                                               const float* __restrict__ ws_f,
                                               unsigned* __restrict__ xq,
                                               unsigned* __restrict__ wqT) {
  const int t = threadIdx.x;
  float sx, st, s_u, q1_u;
  compute_scales(ws_f, t & 63, sx, st, s_u, q1_u);
  if (blockIdx.x < QX_BLOCKS) {
    const int i = blockIdx.x * 256 + t;   // one float4 -> one packed u32 per thread
    const float inv = 1.0f / sx;
    float4 v = ((const float4*)x)[i];
    xq[i] = pack4(v.x, v.y, v.z, v.w, inv);
  } else {
    __shared__ float tile[64][65];
    const int bid = blockIdx.x - QX_BLOCKS;
    const int n0 = (bid & 255) * 64, k0 = (bid >> 8) * 64;
    const float inv = 1.0f / st;
    {
      const int tx = t & 63, ty = t >> 6;
      #pragma unroll
      for (int i = 0; i < 16; ++i) {
        int r = i * 4 + ty;
        tile[r][tx] = w[(size_t)(k0 + r) * N_DIM + n0 + tx];
      }
    }
    __syncthreads();
    // thread -> (k-group kg of 4, n-row nl); LDS reads 2-way aliased (free)
    const int kg = t & 15, nr = t >> 4;
    #pragma unroll
    for (int it = 0; it < 4; ++it) {
      const int nl = it * 16 + nr;
      wqT[((size_t)(n0 + nl) * D_DIM + k0 + kg * 4) >> 2] =
          pack4(tile[kg * 4 + 0][nl], tile[kg * 4 + 1][nl],
                tile[kg * 4 + 2][nl], tile[kg * 4 + 3][nl], inv);
    }
  }
}

// ---------------- GEMM (i8): 128x128 tile, BK=64, 4 waves (2x2), dbuf ----------------
// out[b][n] = ((i32) sum_k qx[b][k]*qw[n][k] + 32*q1*rint(bias[n]/st)) * s
// v_mfma_i32_16x16x64_i8: A/B frag = 16 i8/lane (lane: row=l&15, k=(l>>4)*16..+16).
// LDS: 2 buffers x (A[128][64] + B[128][64]) i8 = 32 KiB -> 4 blocks/CU.
// Chunk swizzle: LDS[r][c] holds global k-chunk c ^ (r&3) (chunks of 16 i8 = 16B).
#define NT 8   // 512 / 64

// stage one K-64 tile: per wave 32 rows of A and of B (2 issues each, 16 rows/issue)
__device__ inline void stage(const char* __restrict__ xq, const char* __restrict__ wqT,
                             int m0, int n0, int kbase, char* buf, int w, int lane) {
  const int rl = lane >> 2;
  const int kc = ((lane & 3) ^ (rl & 3)) * 16;
  #pragma unroll
  for (int i = 0; i < 2; ++i) {
    const int r0 = w * 32 + i * 16;
    gload16(xq + (size_t)(m0 + r0 + rl) * D_DIM + kbase + kc, buf + r0 * 64);
    gload16(wqT + (size_t)(n0 + r0 + rl) * D_DIM + kbase + kc, buf + 8192 + r0 * 64);
  }
}

__global__ __launch_bounds__(256, 4) void k_gemm(const char* __restrict__ xq,
                                                 const char* __restrict__ wqT,
                                                 const float* __restrict__ bias,
                                                 const float* __restrict__ ws_f,
                                                 float* __restrict__ out) {
  __shared__ __align__(16) char lds[2 * 16384];   // buf b: A at b*16384, B at +8192
  const int t = threadIdx.x;
  const int lane = t & 63, w = t >> 6;
  const int wm = w >> 1, wn = w & 1;
  // XCD-chunked swizzle: each XCD gets 16 consecutive n-panels x all 8 m-panels.
  const int nid = (blockIdx.x & 7) * 128 + (blockIdx.x >> 3);
  const int m0 = (nid & 7) * 128;
  const int n0 = (nid >> 3) * 128;

  // prologue: stage tile 0 into buf 0; scales reduce under the loads
  stage(xq, wqT, m0, n0, 0, &lds[0], w, lane);
  float sx_u, st, s, q1;
  compute_scales(ws_f, lane, sx_u, st, s, q1);

  i32x4 acc[4][4] = {};

  for (int T = 0; T < NT; ++T) {
    char* buf = &lds[(T & 1) * 16384];
    asm volatile("s_waitcnt vmcnt(0)" ::: "memory");   // tile T landed (mine)
    __builtin_amdgcn_s_barrier();                      // all landed; all done reading buf^1
    if (T + 1 < NT)
      stage(xq, wqT, m0, n0, (T + 1) * 64, &lds[((T + 1) & 1) * 16384], w, lane);
    i32x4 af[4], bfr[4];
    #pragma unroll
    for (int f = 0; f < 4; ++f) {
      const int ra = wm * 64 + f * 16 + (lane & 15);
      af[f] = *(const i32x4*)&buf[ra * 64 + (((lane >> 4) ^ (ra & 3))) * 16];
      const int rb = wn * 64 + f * 16 + (lane & 15);
      bfr[f] = *(const i32x4*)&buf[8192 + rb * 64 + (((lane >> 4) ^ (rb & 3))) * 16];
    }
    __builtin_amdgcn_s_setprio(1);
    #pragma unroll
    for (int fm = 0; fm < 4; ++fm)
      #pragma unroll
      for (int fn = 0; fn < 4; ++fn)
        acc[fm][fn] = __builtin_amdgcn_mfma_i32_16x16x64_i8(af[fm], bfr[fn], acc[fm][fn], 0, 0, 0);
    __builtin_amdgcn_s_setprio(0);
    __builtin_amdgcn_sched_barrier(0);
  }

  // epilogue: C/D layout col=lane&15, row=(lane>>4)*4+reg; bias term folded in
  #pragma unroll
  for (int fn = 0; fn < 4; ++fn) {
    const int col = n0 + wn * 64 + fn * 16 + (lane & 15);
    const float ba = 32.0f * q1 * rintf(bias[col] / st);
    #pragma unroll
    for (int fm = 0; fm < 4; ++fm) {
      const int rbase = m0 + wm * 64 + fm * 16 + ((lane >> 4) * 4);
      #pragma unroll
      for (int r = 0; r < 4; ++r)
        out[(size_t)(rbase + r) * N_DIM + col] = ((float)acc[fm][fn][r] + ba) * s;
    }
  }
}

extern "C" void kernel_launch(void* const* d_in, const int* in_sizes, int n_in,
                              void* d_out, int out_size, void* d_ws, size_t ws_size,
                              hipStream_t stream) {
  const float* x = (const float*)d_in[0];
  const float* w = (const float*)d_in[1];
  float* out = (float*)d_out;
  char* ws = (char*)d_ws;
  float* ws_f = (float*)ws;
  float* bias = (float*)(ws + OFF_BIAS);
  char* xq = ws + OFF_XQ;
  char* wqT = ws + OFF_WQT;

  hipLaunchKernelGGL(k_stats, dim3(XMAX_BLOCKS + WSTAT_BLOCKS), dim3(256), 0, stream, x, w, ws_f);
  hipLaunchKernelGGL(k_quant, dim3(QX_BLOCKS + 2048), dim3(256), 0, stream, x, w, ws_f,
                     (unsigned*)xq, (unsigned*)wqT);
  hipLaunchKernelGGL(k_gemm, dim3((B_DIM / 128) * (N_DIM / 128)), dim3(256), 0, stream,
                     xq, wqT, bias, ws_f, out);
}

// Round 7
// 41.414 us; speedup vs baseline: 1.9815x; 1.0121x over previous
//
#include <hip/hip_runtime.h>
#include <hip/hip_bf16.h>

// Problem constants (setup_inputs): x[1024][512] f32, weight[512][16384] f32, L=32
#define B_DIM 1024
#define D_DIM 512
#define N_DIM 16384

typedef __attribute__((ext_vector_type(4))) int   i32x4;

// ws layout (f32 indices unless noted):
//   16   : xpart[128]   per-block max|x|
//   256  : wpart[512]   per-block max(|w|, bias)
//   1024 : bias[16384]  bias[n] = sum_k w[k][n]^2 / 32   (ends at f32 idx 17408)
//   byte 73728  : i8 xq[B][D]   (512 KiB)
//   byte 598016 : i8 wqT[N][D]  (8 MiB)
#define IDX_XPART 16
#define IDX_WPART 256
#define IDX_BIAS  1024
#define OFF_XQ    73728
#define OFF_WQT   598016

#define WSTAT_BLOCKS 512
#define XMAX_BLOCKS  128
#define QX_BLOCKS    512   // B*D/4/256

__device__ inline void gload16(const void* g, void* l) {
  __builtin_amdgcn_global_load_lds((const __attribute__((address_space(1))) void*)g,
                                   (__attribute__((address_space(3))) void*)l, 16, 0, 0);
}

__device__ inline unsigned pack4(float a, float b, float c, float d, float inv) {
  int q0 = (int)rintf(a * inv), q1 = (int)rintf(b * inv);
  int q2 = (int)rintf(c * inv), q3 = (int)rintf(d * inv);
  return (q0 & 255) | ((q1 & 255) << 8) | ((q2 & 255) << 16) | ((unsigned)(q3 & 255) << 24);
}

// Every lane computes all scales from the partials (fmax exact -> order-free).
__device__ inline void compute_scales(const float* __restrict__ ws_f, int lane,
                                      float& sx, float& st, float& s, float& q1) {
  float xm = fmaxf(ws_f[IDX_XPART + lane], ws_f[IDX_XPART + 64 + lane]);
  float wm = 0.f;
  #pragma unroll
  for (int j = 0; j < 8; ++j)
    wm = fmaxf(wm, ws_f[IDX_WPART + lane + 64 * j]);
  #pragma unroll
  for (int i = 1; i < 64; i <<= 1) {
    xm = fmaxf(xm, __shfl_xor(xm, i, 64));
    wm = fmaxf(wm, __shfl_xor(wm, i, 64));
  }
  st = fmaxf(wm / 127.0f, 1e-12f);
  sx = fmaxf(fmaxf(xm, 1.0f) / 127.0f, 1e-12f);   // x padded with ones
  s = sx * st;
  q1 = rintf(1.0f / sx);
}

// blocks [0,512): w-stats, 32 cols each (float4 cols, 32 row-parts of 16)
// blocks [512,640): x-max, 4 float4 per thread
__global__ __launch_bounds__(256) void k_stats(const float* __restrict__ x,
                                               const float* __restrict__ w,
                                               float* __restrict__ ws_f) {
  const int t = threadIdx.x;
  const int b = blockIdx.x;
  if (b < WSTAT_BLOCKS) {
    __shared__ float4 s4[256], m4[256];
    const int cg = t & 7, part = t >> 3;            // 8 col-groups x 32 row-parts
    const int col = b * 32 + cg * 4;
    const float4* p = (const float4*)(w + (size_t)(part * 16) * N_DIM + col);
    float4 ss = {0.f, 0.f, 0.f, 0.f}, mx = {0.f, 0.f, 0.f, 0.f};
    #pragma unroll
    for (int d = 0; d < 16; ++d) {
      float4 v = p[(size_t)d * (N_DIM / 4)];
      ss.x += v.x * v.x; ss.y += v.y * v.y; ss.z += v.z * v.z; ss.w += v.w * v.w;
      mx.x = fmaxf(mx.x, fabsf(v.x)); mx.y = fmaxf(mx.y, fabsf(v.y));
      mx.z = fmaxf(mx.z, fabsf(v.z)); mx.w = fmaxf(mx.w, fabsf(v.w));
    }
    s4[t] = ss; m4[t] = mx;
    __syncthreads();
    #pragma unroll
    for (int s = 128; s >= 8; s >>= 1) {
      if (t < s) {
        float4 a = s4[t], c = s4[t + s];
        a.x += c.x; a.y += c.y; a.z += c.z; a.w += c.w; s4[t] = a;
        float4 ma = m4[t], mc = m4[t + s];
        ma.x = fmaxf(ma.x, mc.x); ma.y = fmaxf(ma.y, mc.y);
        ma.z = fmaxf(ma.z, mc.z); ma.w = fmaxf(ma.w, mc.w);
        m4[t] = ma;
      }
      __syncthreads();
    }
    if (t < 8) {
      float4 bs = s4[t];
      bs.x *= (1.0f / 32.0f); bs.y *= (1.0f / 32.0f);
      bs.z *= (1.0f / 32.0f); bs.w *= (1.0f / 32.0f);
      const int c0 = b * 32 + t * 4;
      ws_f[IDX_BIAS + c0 + 0] = bs.x; ws_f[IDX_BIAS + c0 + 1] = bs.y;
      ws_f[IDX_BIAS + c0 + 2] = bs.z; ws_f[IDX_BIAS + c0 + 3] = bs.w;
      float4 mm = m4[t];
      // bias >= 0; scale = max over concat(w, bias rows)
      float m = fmaxf(fmaxf(fmaxf(mm.x, bs.x), fmaxf(mm.y, bs.y)),
                      fmaxf(fmaxf(mm.z, bs.z), fmaxf(mm.w, bs.w)));
      #pragma unroll
      for (int i = 1; i < 8; i <<= 1) m = fmaxf(m, __shfl_xor(m, i, 64));
      if (t == 0) ws_f[IDX_WPART + b] = m;
    }
  } else {
    __shared__ float red[4];
    const float4* x4 = (const float4*)x;
    const int base = (b - WSTAT_BLOCKS) * 1024 + t;
    float m = 0.f;
    #pragma unroll
    for (int j = 0; j < 4; ++j) {
      float4 v = x4[base + j * 256];
      m = fmaxf(m, fmaxf(fmaxf(fabsf(v.x), fabsf(v.y)), fmaxf(fabsf(v.z), fabsf(v.w))));
    }
    #pragma unroll
    for (int i = 1; i < 64; i <<= 1) m = fmaxf(m, __shfl_xor(m, i, 64));
    if ((t & 63) == 0) red[t >> 6] = m;
    __syncthreads();
    if (t == 0)
      ws_f[IDX_XPART + (b - WSTAT_BLOCKS)] =
          fmaxf(fmaxf(red[0], red[1]), fmaxf(red[2], red[3]));
  }
}

// blocks [0,512): quantize x -> xq i8
// blocks [512,2560): quantize + transpose w -> wqT[n][k] i8
__global__ __launch_bounds__(256) void k_quant(const float* __restrict__ x,
                                               const float* __restrict__ w,
                                               const float* __restrict__ ws_f,
                                               unsigned* __restrict__ xq,
                                               unsigned* __restrict__ wqT) {
  const int t = threadIdx.x;
  float sx, st, s_u, q1_u;
  compute_scales(ws_f, t & 63, sx, st, s_u, q1_u);
  if (blockIdx.x < QX_BLOCKS) {
    const int i = blockIdx.x * 256 + t;   // one float4 -> one packed u32 per thread
    const float inv = 1.0f / sx;
    float4 v = ((const float4*)x)[i];
    xq[i] = pack4(v.x, v.y, v.z, v.w, inv);
  } else {
    __shared__ float tile[64][65];
    const int bid = blockIdx.x - QX_BLOCKS;
    const int n0 = (bid & 255) * 64, k0 = (bid >> 8) * 64;
    const float inv = 1.0f / st;
    {
      // float4 loads: 4 passes, row = pass*16 + (t>>4), cols (t&15)*4
      const int r_l = t >> 4, c_l = (t & 15) * 4;
      #pragma unroll
      for (int pass = 0; pass < 4; ++pass) {
        const int r = pass * 16 + r_l;
        float4 v = *(const float4*)&w[(size_t)(k0 + r) * N_DIM + n0 + c_l];
        tile[r][c_l + 0] = v.x; tile[r][c_l + 1] = v.y;
        tile[r][c_l + 2] = v.z; tile[r][c_l + 3] = v.w;
      }
    }
    __syncthreads();
    // thread -> (k-group kg of 4, n-row nl); LDS reads conflict-free (65 pad)
    const int kg = t & 15, nr = t >> 4;
    #pragma unroll
    for (int it = 0; it < 4; ++it) {
      const int nl = it * 16 + nr;
      wqT[((size_t)(n0 + nl) * D_DIM + k0 + kg * 4) >> 2] =
          pack4(tile[kg * 4 + 0][nl], tile[kg * 4 + 1][nl],
                tile[kg * 4 + 2][nl], tile[kg * 4 + 3][nl], inv);
    }
  }
}

// ---------------- GEMM (i8): 128x128 tile, BK=64, 4 waves (2x2), dbuf ----------------
// out[b][n] = ((i32) sum_k qx[b][k]*qw[n][k] + 32*q1*rint(bias[n]/st)) * s
// v_mfma_i32_16x16x64_i8: A/B frag = 16 i8/lane (lane: row=l&15, k=(l>>4)*16..+16).
// LDS: 2 buffers x (A[128][64] + B[128][64]) i8 = 32 KiB -> 4 blocks/CU.
// Chunk swizzle: LDS[r][c] holds global k-chunk c ^ (r&3) (chunks of 16 i8 = 16B).
#define NT 8   // 512 / 64

// stage one K-64 tile: per wave 32 rows of A and of B (2 issues each, 16 rows/issue)
__device__ inline void stage(const char* __restrict__ xq, const char* __restrict__ wqT,
                             int m0, int n0, int kbase, char* buf, int w, int lane) {
  const int rl = lane >> 2;
  const int kc = ((lane & 3) ^ (rl & 3)) * 16;
  #pragma unroll
  for (int i = 0; i < 2; ++i) {
    const int r0 = w * 32 + i * 16;
    gload16(xq + (size_t)(m0 + r0 + rl) * D_DIM + kbase + kc, buf + r0 * 64);
    gload16(wqT + (size_t)(n0 + r0 + rl) * D_DIM + kbase + kc, buf + 8192 + r0 * 64);
  }
}

__global__ __launch_bounds__(256, 4) void k_gemm(const char* __restrict__ xq,
                                                 const char* __restrict__ wqT,
                                                 const float* __restrict__ ws_f,
                                                 float* __restrict__ out) {
  __shared__ __align__(16) char lds[2 * 16384];   // buf b: A at b*16384, B at +8192
  const int t = threadIdx.x;
  const int lane = t & 63, w = t >> 6;
  const int wm = w >> 1, wn = w & 1;
  // XCD-chunked swizzle: each XCD gets 16 consecutive n-panels x all 8 m-panels.
  const int nid = (blockIdx.x & 7) * 128 + (blockIdx.x >> 3);
  const int m0 = (nid & 7) * 128;
  const int n0 = (nid >> 3) * 128;

  // prologue: stage tile 0 into buf 0; scales reduce under the loads
  stage(xq, wqT, m0, n0, 0, &lds[0], w, lane);
  float sx_u, st, s, q1;
  compute_scales(ws_f, lane, sx_u, st, s, q1);

  i32x4 acc[4][4] = {};

  for (int T = 0; T < NT; ++T) {
    char* buf = &lds[(T & 1) * 16384];
    asm volatile("s_waitcnt vmcnt(0)" ::: "memory");   // tile T landed (mine)
    __builtin_amdgcn_s_barrier();                      // all landed; all done reading buf^1
    if (T + 1 < NT)
      stage(xq, wqT, m0, n0, (T + 1) * 64, &lds[((T + 1) & 1) * 16384], w, lane);
    i32x4 af[4], bfr[4];
    #pragma unroll
    for (int f = 0; f < 4; ++f) {
      const int ra = wm * 64 + f * 16 + (lane & 15);
      af[f] = *(const i32x4*)&buf[ra * 64 + (((lane >> 4) ^ (ra & 3))) * 16];
      const int rb = wn * 64 + f * 16 + (lane & 15);
      bfr[f] = *(const i32x4*)&buf[8192 + rb * 64 + (((lane >> 4) ^ (rb & 3))) * 16];
    }
    __builtin_amdgcn_s_setprio(1);
    #pragma unroll
    for (int fm = 0; fm < 4; ++fm)
      #pragma unroll
      for (int fn = 0; fn < 4; ++fn)
        acc[fm][fn] = __builtin_amdgcn_mfma_i32_16x16x64_i8(af[fm], bfr[fn], acc[fm][fn], 0, 0, 0);
    __builtin_amdgcn_s_setprio(0);
    __builtin_amdgcn_sched_barrier(0);
  }

  // epilogue: C/D layout col=lane&15, row=(lane>>4)*4+reg; bias term folded in
  #pragma unroll
  for (int fn = 0; fn < 4; ++fn) {
    const int col = n0 + wn * 64 + fn * 16 + (lane & 15);
    const float ba = 32.0f * q1 * rintf(ws_f[IDX_BIAS + col] / st);
    #pragma unroll
    for (int fm = 0; fm < 4; ++fm) {
      const int rbase = m0 + wm * 64 + fm * 16 + ((lane >> 4) * 4);
      #pragma unroll
      for (int r = 0; r < 4; ++r)
        out[(size_t)(rbase + r) * N_DIM + col] = ((float)acc[fm][fn][r] + ba) * s;
    }
  }
}

extern "C" void kernel_launch(void* const* d_in, const int* in_sizes, int n_in,
                              void* d_out, int out_size, void* d_ws, size_t ws_size,
                              hipStream_t stream) {
  const float* x = (const float*)d_in[0];
  const float* w = (const float*)d_in[1];
  float* out = (float*)d_out;
  char* ws = (char*)d_ws;
  float* ws_f = (float*)ws;
  unsigned* xq = (unsigned*)(ws + OFF_XQ);
  unsigned* wqT = (unsigned*)(ws + OFF_WQT);

  hipLaunchKernelGGL(k_stats, dim3(WSTAT_BLOCKS + XMAX_BLOCKS), dim3(256), 0, stream, x, w, ws_f);
  hipLaunchKernelGGL(k_quant, dim3(QX_BLOCKS + 2048), dim3(256), 0, stream, x, w, ws_f, xq, wqT);
  hipLaunchKernelGGL(k_gemm, dim3((B_DIM / 128) * (N_DIM / 128)), dim3(256), 0, stream,
                     (const char*)xq, (const char*)wqT, ws_f, out);
}